// Round 13
// baseline (131.251 us; speedup 1.0000x reference)
//
#include <hip/hip_runtime.h>
#include <math.h>

// bf16-MFMA MHA v13: flash rebuilt on mfma_f32_32x32x16_bf16 — halves LDS
// bytes/FLOP (16B fragment per 32K FLOP vs 16K), the measured flash bottleneck.
// Wave w owns a 32qx32kv quadrant (qh=w&1, slab=w>>1); K staged through the
// involution pi(row)=swap-bits-2,3 so each lane's 16 score regs (C/D layout
// col q=l&31, row=(reg&3)+8(reg>>2)+4(l>>5), HW-verified m74/m101) pack into
// the PV A-fragment with 8 cvt_pk only. l-sums via ones-MFMA in acc layout.
// Cross-wave (slab) merge by LDS add (no-max softmax => exact).
// Geometry unchanged from the proven point: 64q blocks, 256 thr, 1024 blocks.
// GEMMs: v12 (BK=32, counted-vmcnt, T2 swizzle). Head-pinned flash grid.
// A/B frag layout for 32x32x16 (inferred from verified 16x16x32 pattern):
//   A: lane holds A[l&31][8*(l>>5)+e]   B: lane holds B[8*(l>>5)+e][l&31]

namespace {

constexpr int kHID = 1024;
constexpr int kNH  = 16;
constexpr int kHD  = 64;
constexpr int kSEQ = 2048;

// 1/sqrt(64) * log2(e): scores in log2 domain -> raw exp2f softmax.
constexpr float kQScale = 0.125f * 1.4426950408889634f;

typedef unsigned short ushortT;
typedef __attribute__((ext_vector_type(8)))  short bf16x8;
typedef __attribute__((ext_vector_type(4)))  float f32x4;
typedef __attribute__((ext_vector_type(16))) float f32x16;
typedef __attribute__((ext_vector_type(4)))  unsigned short u16x4;

#define MFMA(a, b, c)   __builtin_amdgcn_mfma_f32_16x16x32_bf16((a), (b), (c), 0, 0, 0)
#define MFMA32(a, b, c) __builtin_amdgcn_mfma_f32_32x32x16_bf16((a), (b), (c), 0, 0, 0)
#define SBAR() __builtin_amdgcn_s_barrier()
#define WAITV0() asm volatile("s_waitcnt vmcnt(0)" ::: "memory")
#define WAITV3() asm volatile("s_waitcnt vmcnt(3)" ::: "memory")
#define WAITV4() asm volatile("s_waitcnt vmcnt(4)" ::: "memory")

typedef const __attribute__((address_space(1))) void GVoid;
typedef __attribute__((address_space(3))) void SVoid;

__device__ __forceinline__ void gload_lds16(const ushortT* g, ushortT* l) {
    __builtin_amdgcn_global_load_lds((GVoid*)g, (SVoid*)l, 16, 0, 0);
}

__device__ __forceinline__ ushortT f2bf(float f) {
    unsigned u = __builtin_bit_cast(unsigned, f);
    u += 0x7fffu + ((u >> 16) & 1u);
    return (ushortT)(u >> 16);
}

__device__ __forceinline__ unsigned cvt_pk_bf16(float a, float b) {
    unsigned r;
    asm("v_cvt_pk_bf16_f32 %0, %1, %2" : "=v"(r) : "v"(a), "v"(b));
    return r;  // low half = bf16(a), high half = bf16(b)
}

__device__ __forceinline__ float4 ld4f(const float* p) { return *reinterpret_cast<const float4*>(p); }

// ---------------------------------------------------------------------------
// Fused prep: blocks [0,4096) convert x fp32->bf16; blocks [4096,5120)
// transpose-convert the 4 weight matrices (64x64 tiles).
// ---------------------------------------------------------------------------
__global__ __launch_bounds__(256) void prep_kernel(
    const float* __restrict__ x, ushortT* __restrict__ xb,
    const float* __restrict__ W0, const float* __restrict__ W1,
    const float* __restrict__ W2, const float* __restrict__ W3,
    ushortT* __restrict__ WtAll) {
    __shared__ ushortT T[64 * 72];
    const int bx = blockIdx.x;
    const int tid = threadIdx.x;

    if (bx < 4096) {   // ---- x convert ----
        const size_t i = ((size_t)bx * 256 + tid) * 4;
        const float4 f = ld4f(&x[i]);
        u16x4 o = { f2bf(f.x), f2bf(f.y), f2bf(f.z), f2bf(f.w) };
        *reinterpret_cast<u16x4*>(&xb[i]) = o;
        return;
    }

    const int id2 = bx - 4096;
    const int z = id2 >> 8;
    const float* W = (z == 0) ? W0 : (z == 1) ? W1 : (z == 2) ? W2 : W3;
    ushortT* Wt = WtAll + (size_t)z * kHID * kHID;
    const int kb = ((id2 >> 4) & 15) * 64, nb = (id2 & 15) * 64;
    {
        const int kr = tid >> 2, nc = (tid & 3) * 16;
        #pragma unroll
        for (int i = 0; i < 16; i += 4) {
            const float4 f = ld4f(&W[(size_t)(kb + kr) * kHID + nb + nc + i]);
            T[kr * 72 + nc + i + 0] = f2bf(f.x);
            T[kr * 72 + nc + i + 1] = f2bf(f.y);
            T[kr * 72 + nc + i + 2] = f2bf(f.z);
            T[kr * 72 + nc + i + 3] = f2bf(f.w);
        }
    }
    __syncthreads();
    {
        const int nr = tid >> 2, kc = (tid & 3) * 16;
        ushortT tmp[16];
        #pragma unroll
        for (int i = 0; i < 16; ++i) tmp[i] = T[(kc + i) * 72 + nr];
        *reinterpret_cast<bf16x8*>(&Wt[(size_t)(nb + nr) * kHID + kb + kc]) =
            *reinterpret_cast<bf16x8*>(&tmp[0]);
        *reinterpret_cast<bf16x8*>(&Wt[(size_t)(nb + nr) * kHID + kb + kc + 8]) =
            *reinterpret_cast<bf16x8*>(&tmp[8]);
    }
}

// ---------------------------------------------------------------------------
// QKV GEMM (v12): 128x128 tile, BK=32, counted-vmcnt pipeline, T2 swizzle.
// ---------------------------------------------------------------------------
__global__ __launch_bounds__(256, 4) void qkv_mfma_gemm(
    const ushortT* __restrict__ A, const ushortT* __restrict__ WtAll,
    const float* __restrict__ bq, const float* __restrict__ bk, const float* __restrict__ bv,
    ushortT* __restrict__ qkvb) {
    __shared__ ushortT As[2 * 4096];
    __shared__ ushortT Bs[2 * 4096];

    const int z = blockIdx.z;
    const ushortT* Bt = WtAll + (size_t)z * kHID * kHID;
    const float* bias = (z == 0) ? bq : (z == 1) ? bk : bv;
    ushortT* out = qkvb + (size_t)z * 2 * kNH * kSEQ * kHD;
    const float scale = (z == 0) ? kQScale : 1.0f;

    const int tid = threadIdx.x, wid = tid >> 6, lane = tid & 63;
    const int hi = lane >> 4, lo = lane & 15;
    const int wr = wid >> 1, wc = wid & 1;
    const int rowBase = blockIdx.y * 128, colBase = blockIdx.x * 128;
    const int sr = lane >> 2, sj = lane & 3;

    const f32x4 z4 = {0.f, 0.f, 0.f, 0.f};
    f32x4 acc[4][4];
    #pragma unroll
    for (int mi = 0; mi < 4; ++mi)
        #pragma unroll
        for (int ni = 0; ni < 4; ++ni) acc[mi][ni] = z4;

    auto STAGE = [&](int buf, int k0) {
        #pragma unroll
        for (int i = 0; i < 2; ++i) {
            const int chunk = wid * 2 + i;
            const int row = chunk * 16 + sr;
            const int c8 = 8 * (sj ^ (sr & 3));
            gload_lds16(&A [(size_t)(rowBase + row) * kHID + k0 + c8], &As[buf * 4096 + chunk * 512]);
            gload_lds16(&Bt[(size_t)(colBase + row) * kHID + k0 + c8], &Bs[buf * 4096 + chunk * 512]);
        }
    };

    STAGE(0, 0);

    for (int t = 0; t < kHID / 32; ++t) {
        const int cur = t & 1;
        if (t + 1 < kHID / 32) {
            STAGE(cur ^ 1, (t + 1) * 32);
            WAITV4();
        } else {
            WAITV0();
        }
        SBAR();

        __builtin_amdgcn_s_setprio(1);
        bf16x8 af[4], bfr[4];
        #pragma unroll
        for (int mi = 0; mi < 4; ++mi) {
            const int row = 64 * wr + 16 * mi + lo;
            af[mi] = *reinterpret_cast<const bf16x8*>(
                &As[cur * 4096 + row * 32 + 8 * (hi ^ (row & 3))]);
        }
        #pragma unroll
        for (int ni = 0; ni < 4; ++ni) {
            const int row = 64 * wc + 16 * ni + lo;
            bfr[ni] = *reinterpret_cast<const bf16x8*>(
                &Bs[cur * 4096 + row * 32 + 8 * (hi ^ (row & 3))]);
        }
        #pragma unroll
        for (int mi = 0; mi < 4; ++mi)
            #pragma unroll
            for (int ni = 0; ni < 4; ++ni)
                acc[mi][ni] = MFMA(af[mi], bfr[ni], acc[mi][ni]);
        __builtin_amdgcn_s_setprio(0);

        SBAR();
    }

    #pragma unroll
    for (int ni = 0; ni < 4; ++ni) {
        const int col = colBase + 64 * wc + 16 * ni + lo;
        const float bcol = bias[col];
        const int h = col >> 6, d = col & 63;
        #pragma unroll
        for (int mi = 0; mi < 4; ++mi)
            #pragma unroll
            for (int r = 0; r < 4; ++r) {
                const int m = rowBase + 64 * wr + 16 * mi + 4 * hi + r;
                const int b = m >> 11, s = m & (kSEQ - 1);
                const ushortT val = f2bf((acc[mi][ni][r] + bcol) * scale);
                if (z == 2)  // V transposed: [B,H,D,S]
                    out[(((size_t)b * kNH + h) * kHD + d) * kSEQ + s] = val;
                else         // Q,K: [B,H,S,D]
                    out[(((size_t)b * kNH + h) * kSEQ + s) * kHD + d] = val;
            }
    }
}

// ---------------------------------------------------------------------------
// Output GEMM (v12): 64M x 128N, BK=32, counted-vmcnt, T2 swizzle.
// ---------------------------------------------------------------------------
__global__ __launch_bounds__(256, 2) void out_mfma_gemm(
    const ushortT* __restrict__ A, const ushortT* __restrict__ Bt,
    const float* __restrict__ bias, float* __restrict__ out) {
    __shared__ ushortT As[2 * 2048];
    __shared__ ushortT Bs[2 * 4096];

    const int tid = threadIdx.x, wid = tid >> 6, lane = tid & 63;
    const int hi = lane >> 4, lo = lane & 15;
    const int wr = wid >> 1, wc = wid & 1;
    const int rowBase = blockIdx.y * 64, colBase = blockIdx.x * 128;
    const int sr = lane >> 2, sj = lane & 3;

    const f32x4 z4 = {0.f, 0.f, 0.f, 0.f};
    f32x4 acc[2][4];
    #pragma unroll
    for (int mi = 0; mi < 2; ++mi)
        #pragma unroll
        for (int ni = 0; ni < 4; ++ni) acc[mi][ni] = z4;

    auto STAGE = [&](int buf, int k0) {
        {
            const int chunk = wid;
            const int row = chunk * 16 + sr;
            const int c8 = 8 * (sj ^ (sr & 3));
            gload_lds16(&A[(size_t)(rowBase + row) * kHID + k0 + c8], &As[buf * 2048 + chunk * 512]);
        }
        #pragma unroll
        for (int i = 0; i < 2; ++i) {
            const int chunk = wid * 2 + i;
            const int row = chunk * 16 + sr;
            const int c8 = 8 * (sj ^ (sr & 3));
            gload_lds16(&Bt[(size_t)(colBase + row) * kHID + k0 + c8], &Bs[buf * 4096 + chunk * 512]);
        }
    };

    STAGE(0, 0);

    for (int t = 0; t < kHID / 32; ++t) {
        const int cur = t & 1;
        if (t + 1 < kHID / 32) {
            STAGE(cur ^ 1, (t + 1) * 32);
            WAITV3();
        } else {
            WAITV0();
        }
        SBAR();

        __builtin_amdgcn_s_setprio(1);
        bf16x8 af[2], bfr[4];
        #pragma unroll
        for (int mi = 0; mi < 2; ++mi) {
            const int row = 32 * wr + 16 * mi + lo;
            af[mi] = *reinterpret_cast<const bf16x8*>(
                &As[cur * 2048 + row * 32 + 8 * (hi ^ (row & 3))]);
        }
        #pragma unroll
        for (int ni = 0; ni < 4; ++ni) {
            const int row = 64 * wc + 16 * ni + lo;
            bfr[ni] = *reinterpret_cast<const bf16x8*>(
                &Bs[cur * 4096 + row * 32 + 8 * (hi ^ (row & 3))]);
        }
        #pragma unroll
        for (int mi = 0; mi < 2; ++mi)
            #pragma unroll
            for (int ni = 0; ni < 4; ++ni)
                acc[mi][ni] = MFMA(af[mi], bfr[ni], acc[mi][ni]);
        __builtin_amdgcn_s_setprio(0);

        SBAR();
    }

    #pragma unroll
    for (int ni = 0; ni < 4; ++ni) {
        const int col = colBase + 64 * wc + 16 * ni + lo;
        const float bcol = bias[col];
        #pragma unroll
        for (int mi = 0; mi < 2; ++mi)
            #pragma unroll
            for (int r = 0; r < 4; ++r) {
                const int m = rowBase + 32 * wr + 16 * mi + 4 * hi + r;
                out[(size_t)m * kHID + col] = acc[mi][ni][r] + bcol;
            }
    }
}

// ---------------------------------------------------------------------------
// MFMA flash attention v13 (32x32x16). Block = (head, 64 q, b), 4 waves:
// wave w -> q-half qh=w&1 (32 q), kv-slab=w>>1 (32 kv of each 64-tile).
// QK^T: sc = sum_c MFMA32(Kfrag[c], Qfrag[c]) -> S^T, lane = one q col.
// K staged via pi(row)=swap bits 2,3 so lane's 16 score regs ARE the PV
// A-fragment after 8 cvt_pk. PV: 2 chunks x 2 d-tiles; l via 2 ones-MFMA.
// Swizzle: 16B chunk ^= (LDSrow&7) on staging source + reads (b128 floor).
// Cross-slab merge via LDS add, then normalize + write.
// ---------------------------------------------------------------------------
__global__ __launch_bounds__(256, 4) void flash_mfma_kernel(
    const ushortT* __restrict__ Qb, const ushortT* __restrict__ Kb,
    const ushortT* __restrict__ Vtg, ushortT* __restrict__ Ob) {
    __shared__ ushortT Ks[2][64 * 64];
    __shared__ ushortT Vs[2][64 * 64];

    const int tid = threadIdx.x, wid = tid >> 6, lane = tid & 63;
    const int l31 = lane & 31, h5 = lane >> 5, l7 = lane & 7;
    const int qh = wid & 1;       // q half (32 rows)
    const int slab = wid >> 1;    // kv slab of each tile
    const int h = blockIdx.x;     // head (XCD-pinned: id%8 == h%8)
    const int q0 = blockIdx.y * 64;
    const size_t headBase = ((size_t)blockIdx.z * kNH + h) * (size_t)(kSEQ * kHD);
    const ushortT* Kg = Kb + headBase;    // [kv][64]
    const ushortT* Vg = Vtg + headBase;   // [d][2048] (pre-transposed)

    // Q B-frags: qf[c] holds Q[q = q0+32qh+l31][d = 16c + 8*h5 + e]
    bf16x8 qf[4];
    #pragma unroll
    for (int c = 0; c < 4; ++c)
        qf[c] = *reinterpret_cast<const bf16x8*>(
            &Qb[headBase + (size_t)(q0 + 32 * qh + l31) * kHD + 16 * c + 8 * h5]);

    const short one = (short)0x3F80;
    const bf16x8 ones = {one, one, one, one, one, one, one, one};

    f32x16 acc0 = {};   // O[q 32][d 0..31]  (C/D: col d=l31, row=(r&3)+8(r>>2)+4h5)
    f32x16 acc1 = {};   // O[q 32][d 32..63]
    f32x16 lacc = {};   // row sums, same row layout

    const int r8 = lane >> 3, jc = lane & 7;   // staging lane decomposition

    // Stage one kv64 tile. LDS rows linear; K source ROW passed through
    // pi (swap bits 2,3); both K and V source 16B-chunk pre-XOR'd by row&7.
    auto STAGE = [&](int buf, int kv0) {
        #pragma unroll
        for (int i = 0; i < 2; ++i) {
            const int rowBase = (i * 4 + wid) * 8;            // wave-uniform
            const int row = rowBase + r8;
            const int ksrc = (row & ~12) | ((row & 4) << 1) | ((row & 8) >> 1);
            const int c8 = 8 * (jc ^ r8);                     // row&7 == r8
            gload_lds16(&Kg[(size_t)(kv0 + ksrc) * kHD + c8], &Ks[buf][rowBase * 64]);
            gload_lds16(&Vg[(size_t)row * kSEQ + kv0 + c8],   &Vs[buf][rowBase * 64]);
        }
    };

    STAGE(0, 0);

    const int krowBase = (32 * slab + l31) * 64;   // K A-frag row (elems)

    for (int t = 0; t < kSEQ / 64; ++t) {
        const int cur = t & 1;
        if (t + 1 < kSEQ / 64) {
            STAGE(cur ^ 1, (t + 1) * 64);
            WAITV4();
        } else {
            WAITV0();
        }
        SBAR();

        // ---- QK^T (4 MFMA32): sc = S^T[kv 32][q 32], lane col q = l31 ----
        f32x16 sc = {};
        __builtin_amdgcn_s_setprio(1);
        #pragma unroll
        for (int c = 0; c < 4; ++c) {
            const bf16x8 kf = *reinterpret_cast<const bf16x8*>(
                &Ks[cur][krowBase + 8 * ((2 * c + h5) ^ l7)]);
            sc = MFMA32(kf, qf[c], sc);
        }
        __builtin_amdgcn_s_setprio(0);

        // ---- softmax (no max-tracking): p = exp2(sc) ----
        float p[16];
        #pragma unroll
        for (int j = 0; j < 16; ++j) p[j] = exp2f(sc[j]);

        // ---- pack PV A-frags: regs 0-7 -> chunk0 (kv 16s..16s+15),
        //      regs 8-15 -> chunk1 (kv 16s+16..): pi makes e-order = kv-order ----
        union U { unsigned u[4]; bf16x8 v; };
        U pa0, pa1;
        #pragma unroll
        for (int j = 0; j < 4; ++j) {
            pa0.u[j] = cvt_pk_bf16(p[2 * j],     p[2 * j + 1]);
            pa1.u[j] = cvt_pk_bf16(p[8 + 2 * j], p[9 + 2 * j]);
        }

        // ---- PV (4 MFMA32) + row sums (2 ones-MFMA32) ----
        __builtin_amdgcn_s_setprio(1);
        lacc = MFMA32(pa0.v, ones, lacc);
        lacc = MFMA32(pa1.v, ones, lacc);
        #pragma unroll
        for (int dt = 0; dt < 2; ++dt) {
            const int vrowBase = (32 * dt + l31) * 64;
            const bf16x8 vf0 = *reinterpret_cast<const bf16x8*>(
                &Vs[cur][vrowBase + 8 * ((4 * slab + h5) ^ l7)]);
            const bf16x8 vf1 = *reinterpret_cast<const bf16x8*>(
                &Vs[cur][vrowBase + 8 * ((4 * slab + 2 + h5) ^ l7)]);
            f32x16& a = dt ? acc1 : acc0;
            a = MFMA32(pa0.v, vf0, a);
            a = MFMA32(pa1.v, vf1, a);
        }
        __builtin_amdgcn_s_setprio(0);

        SBAR();
    }

    // ---- cross-slab merge + epilogue ----
    float* MO = reinterpret_cast<float*>(&Ks[0][0]);   // [2 qh][32 q][64 d] = 16 KB
    float* ML = reinterpret_cast<float*>(&Vs[0][0]);   // [2 qh][32 q]

    if (slab == 1) {
        #pragma unroll
        for (int r = 0; r < 16; ++r) {
            const int qr = (r & 3) + 8 * (r >> 2) + 4 * h5;
            MO[(qh * 32 + qr) * 64 + l31]      = acc0[r];
            MO[(qh * 32 + qr) * 64 + 32 + l31] = acc1[r];
            if (l31 == 0) ML[qh * 32 + qr] = lacc[r];
        }
    }
    __syncthreads();
    if (slab == 0) {
        #pragma unroll
        for (int r = 0; r < 16; ++r) {
            const int qr = (r & 3) + 8 * (r >> 2) + 4 * h5;
            const float o0 = acc0[r] + MO[(qh * 32 + qr) * 64 + l31];
            const float o1 = acc1[r] + MO[(qh * 32 + qr) * 64 + 32 + l31];
            const float inv = 1.0f / (lacc[r] + ML[qh * 32 + qr]);
            const int q = q0 + 32 * qh + qr;
            const size_t base = ((size_t)blockIdx.z * kSEQ + q) * kHID + (size_t)h * kHD;
            Ob[base + l31]      = f2bf(o0 * inv);
            Ob[base + 32 + l31] = f2bf(o1 * inv);
        }
    }
}

}  // namespace

extern "C" void kernel_launch(void* const* d_in, const int* in_sizes, int n_in,
                              void* d_out, int out_size, void* d_ws, size_t ws_size,
                              hipStream_t stream) {
    (void)in_sizes; (void)n_in; (void)out_size;
    const float* x  = (const float*)d_in[0];
    const float* Wq = (const float*)d_in[1];
    const float* bq = (const float*)d_in[2];
    const float* Wk = (const float*)d_in[3];
    const float* bk = (const float*)d_in[4];
    const float* Wv = (const float*)d_in[5];
    const float* bv = (const float*)d_in[6];
    const float* Wo = (const float*)d_in[7];
    const float* bo = (const float*)d_in[8];

    constexpr size_t kXE = (size_t)2 * kSEQ * kHID;   // 4 Mi elems
    constexpr size_t kWE = (size_t)kHID * kHID;       // 1 Mi elems
    const size_t needed = (kXE + 4 * kWE + 3 * kXE + kXE) * sizeof(ushortT);
    if (ws_size < needed) return;

    ushortT* xb    = (ushortT*)d_ws;
    ushortT* WtAll = xb + kXE;
    ushortT* qkvb  = WtAll + 4 * kWE;
    ushortT* attnb = qkvb + 3 * kXE;

    const ushortT* qb  = qkvb;            // [B,H,S,D], pre-scaled by 0.125*log2e
    const ushortT* kb  = qkvb + kXE;      // [B,H,S,D]
    const ushortT* vtb = qkvb + 2 * kXE;  // [B,H,D,S]  (transposed)

    prep_kernel<<<dim3(4096 + 4 * 256), 256, 0, stream>>>(
        x, xb, Wq, Wk, Wv, Wo, WtAll);

    qkv_mfma_gemm<<<dim3(8, 32, 3), 256, 0, stream>>>(xb, WtAll, bq, bk, bv, qkvb);

    // blockIdx.x = head: linear id % 8 == head % 8 -> head pinned to one XCD.
    flash_mfma_kernel<<<dim3(kNH, kSEQ / 64, 2), 256, 0, stream>>>(qb, kb, vtb, attnb);

    out_mfma_gemm<<<dim3(8, 64), 256, 0, stream>>>(attnb, WtAll + 3 * kWE, bo, (float*)d_out);
}

// Round 14
// 126.544 us; speedup vs baseline: 1.0372x; 1.0372x over previous
//
#include <hip/hip_runtime.h>
#include <math.h>

// bf16-MFMA MHA v14 = v12 verbatim (best measured: 127.0 us). v13's 32x32 flash
// reverted: fragment layout was verified correct (absmax held) but perf
// regressed (+4.2e6 bank conflicts, no latency win) — flash is latency-bound,
// not LDS-throughput-bound, so the 16x16 structure at the proven TLP operating
// point is optimal among all tested structures.
// Flash: swapped-QK^T, no max-tracking, ones-MFMA row sums, head-pinned grid,
// counted-vmcnt pipeline. GEMMs: BK=32, counted-vmcnt, T2 swizzle. Fused prep.
// MFMA 16x16x32 bf16 layouts (HW-verified, learn_hip m89/m92):
//   A frag: lane holds A[l&15][8*(l>>4)+e], e=0..7 (k-contiguous bf16x8)
//   B frag: lane holds B[8*(l>>4)+e][l&15]
//   C/D:    lane reg r -> C[(l>>4)*4 + r][l&15]

namespace {

constexpr int kHID = 1024;
constexpr int kNH  = 16;
constexpr int kHD  = 64;
constexpr int kSEQ = 2048;

// 1/sqrt(64) * log2(e): scores in log2 domain -> raw exp2f softmax.
constexpr float kQScale = 0.125f * 1.4426950408889634f;

typedef unsigned short ushortT;
typedef __attribute__((ext_vector_type(8))) short   bf16x8;
typedef __attribute__((ext_vector_type(4))) float   f32x4;
typedef __attribute__((ext_vector_type(4))) unsigned short u16x4;

#define MFMA(a, b, c) __builtin_amdgcn_mfma_f32_16x16x32_bf16((a), (b), (c), 0, 0, 0)
#define SBAR() __builtin_amdgcn_s_barrier()
#define WAITV0() asm volatile("s_waitcnt vmcnt(0)" ::: "memory")
#define WAITV3() asm volatile("s_waitcnt vmcnt(3)" ::: "memory")
#define WAITV4() asm volatile("s_waitcnt vmcnt(4)" ::: "memory")

typedef const __attribute__((address_space(1))) void GVoid;
typedef __attribute__((address_space(3))) void SVoid;

__device__ __forceinline__ void gload_lds16(const ushortT* g, ushortT* l) {
    __builtin_amdgcn_global_load_lds((GVoid*)g, (SVoid*)l, 16, 0, 0);
}

__device__ __forceinline__ ushortT f2bf(float f) {
    unsigned u = __builtin_bit_cast(unsigned, f);
    u += 0x7fffu + ((u >> 16) & 1u);
    return (ushortT)(u >> 16);
}

__device__ __forceinline__ unsigned cvt_pk_bf16(float a, float b) {
    unsigned r;
    asm("v_cvt_pk_bf16_f32 %0, %1, %2" : "=v"(r) : "v"(a), "v"(b));
    return r;  // low half = bf16(a), high half = bf16(b)
}

__device__ __forceinline__ float4 ld4f(const float* p) { return *reinterpret_cast<const float4*>(p); }

// ---------------------------------------------------------------------------
// Fused prep: blocks [0,4096) convert x fp32->bf16 (1024 elems each);
// blocks [4096,5120) transpose-convert the 4 weight matrices (64x64 tiles).
// ---------------------------------------------------------------------------
__global__ __launch_bounds__(256) void prep_kernel(
    const float* __restrict__ x, ushortT* __restrict__ xb,
    const float* __restrict__ W0, const float* __restrict__ W1,
    const float* __restrict__ W2, const float* __restrict__ W3,
    ushortT* __restrict__ WtAll) {
    __shared__ ushortT T[64 * 72];
    const int bx = blockIdx.x;
    const int tid = threadIdx.x;

    if (bx < 4096) {   // ---- x convert ----
        const size_t i = ((size_t)bx * 256 + tid) * 4;
        const float4 f = ld4f(&x[i]);
        u16x4 o = { f2bf(f.x), f2bf(f.y), f2bf(f.z), f2bf(f.w) };
        *reinterpret_cast<u16x4*>(&xb[i]) = o;
        return;
    }

    // ---- weight transpose: id2 = z*256 + (kb16)*16 + nb16 ----
    const int id2 = bx - 4096;
    const int z = id2 >> 8;
    const float* W = (z == 0) ? W0 : (z == 1) ? W1 : (z == 2) ? W2 : W3;
    ushortT* Wt = WtAll + (size_t)z * kHID * kHID;
    const int kb = ((id2 >> 4) & 15) * 64, nb = (id2 & 15) * 64;
    {
        const int kr = tid >> 2, nc = (tid & 3) * 16;
        #pragma unroll
        for (int i = 0; i < 16; i += 4) {
            const float4 f = ld4f(&W[(size_t)(kb + kr) * kHID + nb + nc + i]);
            T[kr * 72 + nc + i + 0] = f2bf(f.x);
            T[kr * 72 + nc + i + 1] = f2bf(f.y);
            T[kr * 72 + nc + i + 2] = f2bf(f.z);
            T[kr * 72 + nc + i + 3] = f2bf(f.w);
        }
    }
    __syncthreads();
    {
        const int nr = tid >> 2, kc = (tid & 3) * 16;
        ushortT tmp[16];
        #pragma unroll
        for (int i = 0; i < 16; ++i) tmp[i] = T[(kc + i) * 72 + nr];
        *reinterpret_cast<bf16x8*>(&Wt[(size_t)(nb + nr) * kHID + kb + kc]) =
            *reinterpret_cast<bf16x8*>(&tmp[0]);
        *reinterpret_cast<bf16x8*>(&Wt[(size_t)(nb + nr) * kHID + kb + kc + 8]) =
            *reinterpret_cast<bf16x8*>(&tmp[8]);
    }
}

// ---------------------------------------------------------------------------
// QKV GEMM: 128x128 tile, BK=32 (LDS 32KB -> 3+ blocks/CU). Counted-vmcnt
// pipeline. Swizzle: LDS[row][chunk] holds G[row][chunk^(row&3)];
// frag read at chunk hi^(row&3) -> banks 2-way max (free).
// Q scaled; V transposed [B,H,D,S].
// ---------------------------------------------------------------------------
__global__ __launch_bounds__(256, 4) void qkv_mfma_gemm(
    const ushortT* __restrict__ A, const ushortT* __restrict__ WtAll,
    const float* __restrict__ bq, const float* __restrict__ bk, const float* __restrict__ bv,
    ushortT* __restrict__ qkvb) {
    __shared__ ushortT As[2 * 4096];
    __shared__ ushortT Bs[2 * 4096];

    const int z = blockIdx.z;
    const ushortT* Bt = WtAll + (size_t)z * kHID * kHID;
    const float* bias = (z == 0) ? bq : (z == 1) ? bk : bv;
    ushortT* out = qkvb + (size_t)z * 2 * kNH * kSEQ * kHD;
    const float scale = (z == 0) ? kQScale : 1.0f;

    const int tid = threadIdx.x, wid = tid >> 6, lane = tid & 63;
    const int hi = lane >> 4, lo = lane & 15;
    const int wr = wid >> 1, wc = wid & 1;
    const int rowBase = blockIdx.y * 128, colBase = blockIdx.x * 128;
    const int sr = lane >> 2, sj = lane & 3;   // staging: 16 rows x 4 chunks per instr

    const f32x4 z4 = {0.f, 0.f, 0.f, 0.f};
    f32x4 acc[4][4];
    #pragma unroll
    for (int mi = 0; mi < 4; ++mi)
        #pragma unroll
        for (int ni = 0; ni < 4; ++ni) acc[mi][ni] = z4;

    // Stage one 128x32 tile pair. Linear LDS dest; source chunk pre-XOR'd by row&3.
    auto STAGE = [&](int buf, int k0) {
        #pragma unroll
        for (int i = 0; i < 2; ++i) {
            const int chunk = wid * 2 + i;                 // wave-uniform
            const int row = chunk * 16 + sr;
            const int c8 = 8 * (sj ^ (sr & 3));            // row&3 == sr&3
            gload_lds16(&A [(size_t)(rowBase + row) * kHID + k0 + c8], &As[buf * 4096 + chunk * 512]);
            gload_lds16(&Bt[(size_t)(colBase + row) * kHID + k0 + c8], &Bs[buf * 4096 + chunk * 512]);
        }
    };

    STAGE(0, 0);

    for (int t = 0; t < kHID / 32; ++t) {
        const int cur = t & 1;
        if (t + 1 < kHID / 32) {
            STAGE(cur ^ 1, (t + 1) * 32);
            WAITV4();                        // retire exactly tile t's 4 loads
        } else {
            WAITV0();
        }
        SBAR();

        __builtin_amdgcn_s_setprio(1);
        bf16x8 af[4], bfr[4];
        #pragma unroll
        for (int mi = 0; mi < 4; ++mi) {
            const int row = 64 * wr + 16 * mi + lo;
            af[mi] = *reinterpret_cast<const bf16x8*>(
                &As[cur * 4096 + row * 32 + 8 * (hi ^ (row & 3))]);
        }
        #pragma unroll
        for (int ni = 0; ni < 4; ++ni) {
            const int row = 64 * wc + 16 * ni + lo;
            bfr[ni] = *reinterpret_cast<const bf16x8*>(
                &Bs[cur * 4096 + row * 32 + 8 * (hi ^ (row & 3))]);
        }
        #pragma unroll
        for (int mi = 0; mi < 4; ++mi)
            #pragma unroll
            for (int ni = 0; ni < 4; ++ni)
                acc[mi][ni] = MFMA(af[mi], bfr[ni], acc[mi][ni]);
        __builtin_amdgcn_s_setprio(0);

        SBAR();
    }

    #pragma unroll
    for (int ni = 0; ni < 4; ++ni) {
        const int col = colBase + 64 * wc + 16 * ni + lo;
        const float bcol = bias[col];
        const int h = col >> 6, d = col & 63;
        #pragma unroll
        for (int mi = 0; mi < 4; ++mi)
            #pragma unroll
            for (int r = 0; r < 4; ++r) {
                const int m = rowBase + 64 * wr + 16 * mi + 4 * hi + r;
                const int b = m >> 11, s = m & (kSEQ - 1);
                const ushortT val = f2bf((acc[mi][ni][r] + bcol) * scale);
                if (z == 2)  // V transposed: [B,H,D,S]
                    out[(((size_t)b * kNH + h) * kHD + d) * kSEQ + s] = val;
                else         // Q,K: [B,H,S,D]
                    out[(((size_t)b * kNH + h) * kSEQ + s) * kHD + d] = val;
            }
    }
}

// ---------------------------------------------------------------------------
// Output GEMM: 64M x 128N tiles, BK=32 -> 512 blocks (2/CU).
// attnb bf16 @ Wo (as Wt) + bo -> fp32 d_out. Same swizzle/pipeline.
// ---------------------------------------------------------------------------
__global__ __launch_bounds__(256, 2) void out_mfma_gemm(
    const ushortT* __restrict__ A, const ushortT* __restrict__ Bt,
    const float* __restrict__ bias, float* __restrict__ out) {
    __shared__ ushortT As[2 * 2048];
    __shared__ ushortT Bs[2 * 4096];

    const int tid = threadIdx.x, wid = tid >> 6, lane = tid & 63;
    const int hi = lane >> 4, lo = lane & 15;
    const int wr = wid >> 1, wc = wid & 1;
    const int rowBase = blockIdx.y * 64, colBase = blockIdx.x * 128;
    const int sr = lane >> 2, sj = lane & 3;

    const f32x4 z4 = {0.f, 0.f, 0.f, 0.f};
    f32x4 acc[2][4];
    #pragma unroll
    for (int mi = 0; mi < 2; ++mi)
        #pragma unroll
        for (int ni = 0; ni < 4; ++ni) acc[mi][ni] = z4;

    // Stage: A 64x32 (4 instr, 1/wave) + B 128x32 (8 instr, 2/wave) = 3/wave.
    auto STAGE = [&](int buf, int k0) {
        {
            const int chunk = wid;                          // wave-uniform
            const int row = chunk * 16 + sr;
            const int c8 = 8 * (sj ^ (sr & 3));
            gload_lds16(&A[(size_t)(rowBase + row) * kHID + k0 + c8], &As[buf * 2048 + chunk * 512]);
        }
        #pragma unroll
        for (int i = 0; i < 2; ++i) {
            const int chunk = wid * 2 + i;
            const int row = chunk * 16 + sr;
            const int c8 = 8 * (sj ^ (sr & 3));
            gload_lds16(&Bt[(size_t)(colBase + row) * kHID + k0 + c8], &Bs[buf * 4096 + chunk * 512]);
        }
    };

    STAGE(0, 0);

    for (int t = 0; t < kHID / 32; ++t) {
        const int cur = t & 1;
        if (t + 1 < kHID / 32) {
            STAGE(cur ^ 1, (t + 1) * 32);
            WAITV3();                        // retire exactly tile t's 3 loads
        } else {
            WAITV0();
        }
        SBAR();

        __builtin_amdgcn_s_setprio(1);
        bf16x8 af[2], bfr[4];
        #pragma unroll
        for (int mi = 0; mi < 2; ++mi) {
            const int row = 32 * wr + 16 * mi + lo;
            af[mi] = *reinterpret_cast<const bf16x8*>(
                &As[cur * 2048 + row * 32 + 8 * (hi ^ (row & 3))]);
        }
        #pragma unroll
        for (int ni = 0; ni < 4; ++ni) {
            const int row = 64 * wc + 16 * ni + lo;
            bfr[ni] = *reinterpret_cast<const bf16x8*>(
                &Bs[cur * 4096 + row * 32 + 8 * (hi ^ (row & 3))]);
        }
        #pragma unroll
        for (int mi = 0; mi < 2; ++mi)
            #pragma unroll
            for (int ni = 0; ni < 4; ++ni)
                acc[mi][ni] = MFMA(af[mi], bfr[ni], acc[mi][ni]);
        __builtin_amdgcn_s_setprio(0);

        SBAR();
    }

    #pragma unroll
    for (int ni = 0; ni < 4; ++ni) {
        const int col = colBase + 64 * wc + 16 * ni + lo;
        const float bcol = bias[col];
        #pragma unroll
        for (int mi = 0; mi < 2; ++mi)
            #pragma unroll
            for (int r = 0; r < 4; ++r) {
                const int m = rowBase + 32 * wr + 16 * mi + 4 * hi + r;
                out[(size_t)m * kHID + col] = acc[mi][ni][r] + bcol;
            }
    }
}

// ---------------------------------------------------------------------------
// MFMA flash attention (v11 structure — best measured). Block = (head,
// 64 q-rows, b); head-pinned grid (id%8 == h%8). 4 waves x 16 q-rows,
// swapped QK^T, no max-tracking, ones-MFMA row sums. K/V^T dbuf via
// global_load_lds w=16 pre-swizzled source; s(row) = (row&3)|(((row>>3)&1)<<2).
// Pipeline: STAGE(t+1) -> vmcnt(4) -> s_barrier -> compute(t) -> s_barrier.
// ---------------------------------------------------------------------------
__global__ __launch_bounds__(256, 4) void flash_mfma_kernel(
    const ushortT* __restrict__ Qb, const ushortT* __restrict__ Kb,
    const ushortT* __restrict__ Vtg, ushortT* __restrict__ Ob) {
    __shared__ ushortT Ks[2][64 * 64];
    __shared__ ushortT Vs[2][64 * 64];

    const int tid = threadIdx.x, wid = tid >> 6, lane = tid & 63;
    const int hi = lane >> 4, lo = lane & 15;
    const int h = blockIdx.x;                  // head (XCD-pinned: id%8 == h%8)
    const int q0 = blockIdx.y * 64;
    const size_t headBase = ((size_t)blockIdx.z * kNH + h) * (size_t)(kSEQ * kHD);
    const ushortT* Kg = Kb + headBase;    // [kv][64]
    const ushortT* Vg = Vtg + headBase;   // [d][2048] (pre-transposed)

    bf16x8 qf[2];
    #pragma unroll
    for (int c = 0; c < 2; ++c)
        qf[c] = *reinterpret_cast<const bf16x8*>(
            &Qb[headBase + (size_t)(q0 + 16 * wid + lo) * kHD + 32 * c + 8 * hi]);

    const short one = (short)0x3F80;
    const bf16x8 ones = {one, one, one, one, one, one, one, one};

    const f32x4 z4 = {0.f, 0.f, 0.f, 0.f};
    f32x4 acc[4] = {z4, z4, z4, z4};
    f32x4 accL = z4;

    const int r8 = lane >> 3, jc = lane & 7;

    const int kap0 = 8 * (lo >> 2) + (lo & 3);
    const int sk = (lo & 3) | (((lo >> 2) & 1) << 2);
    const int kx0 = (8 * hi) ^ (sk << 3);
    const int kx1 = (32 + 8 * hi) ^ (sk << 3);
    const int sv = (lo & 3) | (((lo >> 3) & 1) << 2);

    auto STAGE = [&](int buf, int kv0) {
        #pragma unroll
        for (int i = 0; i < 2; ++i) {
            const int rowBase = (i * 4 + wid) * 8;
            const int row = rowBase + r8;
            const int s8 = (r8 & 3) | ((wid & 1) << 2);
            gload_lds16(&Kg[(size_t)(kv0 + row) * kHD + 8 * (jc ^ s8)], &Ks[buf][rowBase * 64]);
            gload_lds16(&Vg[(size_t)row * kSEQ + kv0 + 8 * (jc ^ s8)], &Vs[buf][rowBase * 64]);
        }
    };

    STAGE(0, 0);

    for (int t = 0; t < kSEQ / 64; ++t) {
        const int cur = t & 1;
        if (t + 1 < kSEQ / 64) {
            STAGE(cur ^ 1, (t + 1) * 64);
            WAITV4();
        } else {
            WAITV0();
        }
        SBAR();

        f32x4 sc[4];
        __builtin_amdgcn_s_setprio(1);
        #pragma unroll
        for (int f = 0; f < 4; ++f) {
            const int kap = kap0 + 4 * (f & 1) + 32 * (f >> 1);
            const bf16x8 kf0 = *reinterpret_cast<const bf16x8*>(&Ks[cur][kap * 64 + kx0]);
            const bf16x8 kf1 = *reinterpret_cast<const bf16x8*>(&Ks[cur][kap * 64 + kx1]);
            sc[f] = MFMA(kf1, qf[1], MFMA(kf0, qf[0], z4));
        }
        __builtin_amdgcn_s_setprio(0);

        float p[4][4];
        #pragma unroll
        for (int f = 0; f < 4; ++f)
            #pragma unroll
            for (int r = 0; r < 4; ++r) p[f][r] = exp2f(sc[f][r]);

        union U { unsigned u[4]; bf16x8 v; };
        U pa0, pa1;
        pa0.u[0] = cvt_pk_bf16(p[0][0], p[0][1]);
        pa0.u[1] = cvt_pk_bf16(p[0][2], p[0][3]);
        pa0.u[2] = cvt_pk_bf16(p[1][0], p[1][1]);
        pa0.u[3] = cvt_pk_bf16(p[1][2], p[1][3]);
        pa1.u[0] = cvt_pk_bf16(p[2][0], p[2][1]);
        pa1.u[1] = cvt_pk_bf16(p[2][2], p[2][3]);
        pa1.u[2] = cvt_pk_bf16(p[3][0], p[3][1]);
        pa1.u[3] = cvt_pk_bf16(p[3][2], p[3][3]);

        __builtin_amdgcn_s_setprio(1);
        accL = MFMA(pa0.v, ones, accL);
        accL = MFMA(pa1.v, ones, accL);
        #pragma unroll
        for (int n = 0; n < 4; ++n) {
            const int vrow = 16 * n + lo;
            const bf16x8 vf0 = *reinterpret_cast<const bf16x8*>(
                &Vs[cur][vrow * 64 + ((8 * hi) ^ (sv << 3))]);
            const bf16x8 vf1 = *reinterpret_cast<const bf16x8*>(
                &Vs[cur][vrow * 64 + ((32 + 8 * hi) ^ (sv << 3))]);
            acc[n] = MFMA(pa0.v, vf0, acc[n]);
            acc[n] = MFMA(pa1.v, vf1, acc[n]);
        }
        __builtin_amdgcn_s_setprio(0);

        SBAR();
    }

    #pragma unroll
    for (int r = 0; r < 4; ++r) {
        const float inv = 1.0f / accL[r];
        const int s = q0 + 16 * wid + 4 * hi + r;
        const size_t base = ((size_t)blockIdx.z * kSEQ + s) * kHID + (size_t)h * kHD;
        #pragma unroll
        for (int n = 0; n < 4; ++n)
            Ob[base + 16 * n + lo] = f2bf(acc[n][r] * inv);
    }
}

}  // namespace

extern "C" void kernel_launch(void* const* d_in, const int* in_sizes, int n_in,
                              void* d_out, int out_size, void* d_ws, size_t ws_size,
                              hipStream_t stream) {
    (void)in_sizes; (void)n_in; (void)out_size;
    const float* x  = (const float*)d_in[0];
    const float* Wq = (const float*)d_in[1];
    const float* bq = (const float*)d_in[2];
    const float* Wk = (const float*)d_in[3];
    const float* bk = (const float*)d_in[4];
    const float* Wv = (const float*)d_in[5];
    const float* bv = (const float*)d_in[6];
    const float* Wo = (const float*)d_in[7];
    const float* bo = (const float*)d_in[8];

    constexpr size_t kXE = (size_t)2 * kSEQ * kHID;   // 4 Mi elems
    constexpr size_t kWE = (size_t)kHID * kHID;       // 1 Mi elems
    const size_t needed = (kXE + 4 * kWE + 3 * kXE + kXE) * sizeof(ushortT);
    if (ws_size < needed) return;

    ushortT* xb    = (ushortT*)d_ws;
    ushortT* WtAll = xb + kXE;
    ushortT* qkvb  = WtAll + 4 * kWE;
    ushortT* attnb = qkvb + 3 * kXE;

    const ushortT* qb  = qkvb;            // [B,H,S,D], pre-scaled by 0.125*log2e
    const ushortT* kb  = qkvb + kXE;      // [B,H,S,D]
    const ushortT* vtb = qkvb + 2 * kXE;  // [B,H,D,S]  (transposed)

    // fused x-convert + weight-transpose (one launch, independent work)
    prep_kernel<<<dim3(4096 + 4 * 256), 256, 0, stream>>>(
        x, xb, Wq, Wk, Wv, Wo, WtAll);

    qkv_mfma_gemm<<<dim3(8, 32, 3), 256, 0, stream>>>(xb, WtAll, bq, bk, bv, qkvb);

    // blockIdx.x = head: linear id % 8 == head % 8 -> head pinned to one XCD.
    flash_mfma_kernel<<<dim3(kNH, kSEQ / 64, 2), 256, 0, stream>>>(qb, kb, vtb, attnb);

    out_mfma_gemm<<<dim3(8, 64), 256, 0, stream>>>(attnb, WtAll + 3 * kWE, bo, (float*)d_out);
}